// Round 2
// baseline (454.280 us; speedup 1.0000x reference)
//
#include <hip/hip_runtime.h>

// R2: s2 128x128 triangle grid + global_load_lds everywhere; s1 128-row tiles
// with double-buffered 1-barrier K prefetch; algebraic removal of vo/Wvo
// intermediates (WvoT and voT computed directly); ws ~58MB.

#define L_SEQ 2048
#define NBATCH 4
#define DMODEL 1024
#define NHEAD 8
#define SCALING 0.08838834764831845f

typedef _Float16 f16x8 __attribute__((ext_vector_type(8)));
typedef float f32x4 __attribute__((ext_vector_type(4)));

#define GLOBAL_AS __attribute__((address_space(1)))
#define LDS_AS __attribute__((address_space(3)))

__device__ __forceinline__ unsigned short f2h_bits(float x) {
  _Float16 h = (_Float16)x;
  return __builtin_bit_cast(unsigned short, h);
}

// Direct global->LDS DMA, 16B per lane. LDS dest = wave-uniform base + lane*16
// (hardware rule, m104); global src is per-lane. Swizzled layouts are achieved
// by pre-swizzling the SOURCE chunk index (m173).
__device__ __forceinline__ void gl_lds16(const void* g, void* l) {
  __builtin_amdgcn_global_load_lds((GLOBAL_AS void*)g, (LDS_AS void*)l, 16, 0, 0);
}

// ---------------------------------------------------------------------------
// GEMM: C/Ch = (A @ Bt^T + bias) * alpha
//   A: MxK row-major (f32 if !AF16 else f16). Bt: NxK row-major (B^T).
//   f16 operands staged via global_load_lds with pre-swizzled source chunks;
//   f32 operands staged via load+cvt+swizzled ds_write.
//   causal: K limited to m0+128 (A cols beyond block-diag are zero).
// Tile 128x128, BK=64, 4 waves (2x2 of 64x64), mfma 16x16x32 f16.
// LDS tiles [128][64] f16, XOR-swizzle chunk^=(row&7) (16B units).
// ---------------------------------------------------------------------------
template <bool AF16, bool BF16>
__global__ __launch_bounds__(256) void gemm16(
    const void* __restrict__ Ap, long lda, long a_bs,
    const void* __restrict__ Bp, long ldb, long b_bs,
    float* __restrict__ C, long ldc, long c_bs,
    _Float16* __restrict__ Ch, long ldch, long ch_bs,
    const float* __restrict__ bias, int bias_row, float alpha, int K, int causal)
{
  __shared__ __align__(16) _Float16 As[128][64];
  __shared__ __align__(16) _Float16 Bs[128][64];
  const int tid = threadIdx.x;
  const int lane = tid & 63, wv = tid >> 6;
  const int g = lane >> 4, cc = lane & 15;
  const int wm = wv >> 1, wn = wv & 1;
  const long m0 = (long)blockIdx.y * 128;
  const long n0 = (long)blockIdx.x * 128;

  const float* Af = nullptr; const _Float16* Ah = nullptr;
  const float* Bf = nullptr; const _Float16* Bh = nullptr;
  if constexpr (AF16) Ah = (const _Float16*)Ap + (long)blockIdx.z * a_bs;
  else                Af = (const float*)Ap + (long)blockIdx.z * a_bs;
  if constexpr (BF16) Bh = (const _Float16*)Bp + (long)blockIdx.z * b_bs;
  else                Bf = (const float*)Bp + (long)blockIdx.z * b_bs;

  int Keff = K;
  if (causal) { int lim = (int)m0 + 128; if (lim < K) Keff = lim; }
  const int NT = Keff >> 6;

  f32x4 acc[4][4] = {};
  char* AsB = (char*)&As[0][0];
  char* BsB = (char*)&Bs[0][0];

  for (int kt = 0; kt < NT; ++kt) {
    const long k0 = (long)kt << 6;
    __syncthreads();
    if constexpr (AF16) {
      // wave wv stages rows 32wv..32wv+31: 4 instrs, 8 rows each (128B rows)
#pragma unroll
      for (int i = 0; i < 4; ++i) {
        int r = 32 * wv + 8 * i + (lane >> 3);
        int gc = (lane & 7) ^ (r & 7);
        gl_lds16(Ah + (m0 + r) * lda + k0 + gc * 8, &As[32 * wv + 8 * i][0]);
      }
    } else {
#pragma unroll
      for (int p = 0; p < 8; ++p) {
        int r = p * 16 + (tid >> 4);
        float4 vv = *(const float4*)(Af + (m0 + r) * lda + k0 + (tid & 15) * 4);
        ushort4 hh;
        hh.x = f2h_bits(vv.x); hh.y = f2h_bits(vv.y);
        hh.z = f2h_bits(vv.z); hh.w = f2h_bits(vv.w);
        *(ushort4*)(AsB + r * 128 + (((tid & 15) * 8) ^ ((r & 7) << 4))) = hh;
      }
    }
    if constexpr (BF16) {
#pragma unroll
      for (int i = 0; i < 4; ++i) {
        int r = 32 * wv + 8 * i + (lane >> 3);
        int gc = (lane & 7) ^ (r & 7);
        gl_lds16(Bh + (n0 + r) * ldb + k0 + gc * 8, &Bs[32 * wv + 8 * i][0]);
      }
    } else {
#pragma unroll
      for (int p = 0; p < 8; ++p) {
        int r = p * 16 + (tid >> 4);
        float4 vv = *(const float4*)(Bf + (n0 + r) * ldb + k0 + (tid & 15) * 4);
        ushort4 hh;
        hh.x = f2h_bits(vv.x); hh.y = f2h_bits(vv.y);
        hh.z = f2h_bits(vv.z); hh.w = f2h_bits(vv.w);
        *(ushort4*)(BsB + r * 128 + (((tid & 15) * 8) ^ ((r & 7) << 4))) = hh;
      }
    }
    __syncthreads();
#pragma unroll
    for (int s = 0; s < 2; ++s) {
      f16x8 af[4], bfr[4];
#pragma unroll
      for (int mi = 0; mi < 4; ++mi) {
        int r = wm * 64 + mi * 16 + cc;
        af[mi] = *(const f16x8*)(AsB + r * 128 + ((s * 64 + 16 * g) ^ ((r & 7) << 4)));
      }
#pragma unroll
      for (int ni = 0; ni < 4; ++ni) {
        int r = wn * 64 + ni * 16 + cc;
        bfr[ni] = *(const f16x8*)(BsB + r * 128 + ((s * 64 + 16 * g) ^ ((r & 7) << 4)));
      }
#pragma unroll
      for (int mi = 0; mi < 4; ++mi)
#pragma unroll
        for (int ni = 0; ni < 4; ++ni)
          acc[mi][ni] = __builtin_amdgcn_mfma_f32_16x16x32_f16(af[mi], bfr[ni], acc[mi][ni], 0, 0, 0);
    }
  }

  float* Cp = C ? C + (long)blockIdx.z * c_bs : nullptr;
  _Float16* Chp = Ch ? Ch + (long)blockIdx.z * ch_bs : nullptr;
#pragma unroll
  for (int ni = 0; ni < 4; ++ni) {
    long col = n0 + wn * 64 + ni * 16 + cc;
    float bcol = (bias && !bias_row) ? bias[col] : 0.0f;
#pragma unroll
    for (int mi = 0; mi < 4; ++mi) {
      long row0 = m0 + wm * 64 + mi * 16 + 4 * g;
#pragma unroll
      for (int rg = 0; rg < 4; ++rg) {
        float b = (bias && bias_row) ? bias[row0 + rg] : bcol;
        float vv = (acc[mi][ni][rg] + b) * alpha;
        if (Cp)  Cp[(row0 + rg) * ldc + col] = vv;
        if (Chp) Chp[(row0 + rg) * ldch + col] = (_Float16)vv;
      }
    }
  }
}

// ---------------------------------------------------------------------------
// Transpose + cast f32 -> f16 (weights): out[c*R + r] = in[r*rs + c]
// ---------------------------------------------------------------------------
__global__ __launch_bounds__(256) void transpose_cast_f32(
    const float* __restrict__ in, long rs,
    _Float16* __restrict__ outp, int R)
{
  __shared__ _Float16 tile[32][33];
  int r0 = blockIdx.y * 32, c0 = blockIdx.x * 32;
  for (int i = threadIdx.y; i < 32; i += 8)
    tile[i][threadIdx.x] = (_Float16)in[(long)(r0 + i) * rs + c0 + threadIdx.x];
  __syncthreads();
  for (int i = threadIdx.y; i < 32; i += 8)
    outp[(long)(c0 + i) * R + r0 + threadIdx.x] = tile[threadIdx.x][i];
}

// bvo[j] = sum_i bv[i] * Wo[i][j]
__global__ __launch_bounds__(256) void bias_proj(
    const float* __restrict__ bv, const float* __restrict__ Wo, float* __restrict__ bvo)
{
  int j = blockIdx.x * 256 + threadIdx.x;
  float acc = 0.f;
  for (int i = 0; i < DMODEL; ++i) acc += bv[i] * Wo[(long)i * DMODEL + j];
  bvo[j] = acc;
}

// ---------------------------------------------------------------------------
// S1: Zinv[n,h,l] = 1 / (8 * sum_{m<=l} exp(qp_h[l,:].kp_h[m,:]))
// Block = (128 l-rows, h, n). Q staged once (32KB); K double-buffered 64-row
// chunks with 1-barrier prefetch loop (DMA of chunk ch+1 in flight under
// compute of chunk ch). 4 waves x 32 rows.
// ---------------------------------------------------------------------------
__global__ __launch_bounds__(256) void s1_kernel(
    const _Float16* __restrict__ qp, const _Float16* __restrict__ kp,
    float* __restrict__ Zinv)
{
  __shared__ __align__(16) _Float16 Qs[128][128];
  __shared__ __align__(16) _Float16 Ks[2][64][128];
  const int tid = threadIdx.x, lane = tid & 63, w = tid >> 6;
  const int g = lane >> 4, cc = lane & 15;
  const int by = (int)(gridDim.x - 1) - (int)blockIdx.x;  // long blocks first
  const int h = blockIdx.y, nb = blockIdx.z;
  const int lb = by * 128;
  const int srow = lane >> 4, scl = lane & 15;
  char* QsB = (char*)&Qs[0][0];

  // stage Q rows 32w..32w+31 (8 instrs x 4 rows; 256B rows, 16 chunks)
#pragma unroll
  for (int i = 0; i < 8; ++i) {
    int r = 32 * w + 4 * i + srow;
    int gc = scl ^ (r & 7);
    gl_lds16(&qp[((long)(lb + r) * 4 + nb) * 1024 + h * 128 + gc * 8],
             &Qs[32 * w + 4 * i][0]);
  }
  auto stageK = [&](int ch, int buf) {
#pragma unroll
    for (int i = 0; i < 4; ++i) {
      int r = 16 * w + 4 * i + srow;
      int gc = scl ^ (r & 7);
      gl_lds16(&kp[((long)(ch * 64 + r) * 4 + nb) * 1024 + h * 128 + gc * 8],
               &Ks[buf][16 * w + 4 * i][0]);
    }
  };
  stageK(0, 0);
  __syncthreads();

  f16x8 qf[2][4];
#pragma unroll
  for (int u = 0; u < 2; ++u) {
    int r = 32 * w + 16 * u + cc;
#pragma unroll
    for (int s = 0; s < 4; ++s)
      qf[u][s] = *(const f16x8*)(QsB + r * 256 + ((64 * s + 16 * g) ^ ((r & 7) << 4)));
  }

  float zacc[2][4] = {};
  const int nch = 2 * by + 2;
  const int wmax = lb + 32 * w + 31;
  for (int ch = 0; ch < nch; ++ch) {
    if (ch) __syncthreads();                 // K(ch) DMA drained; buf free
    if (ch + 1 < nch) stageK(ch + 1, (ch + 1) & 1);
    if (ch * 64 <= wmax) {
      char* KsB = (char*)&Ks[ch & 1][0][0];
#pragma unroll
      for (int t = 0; t < 4; ++t) {
        int kr = 16 * t + cc;
        f16x8 kf[4];
#pragma unroll
        for (int s = 0; s < 4; ++s)
          kf[s] = *(const f16x8*)(KsB + kr * 256 + ((64 * s + 16 * g) ^ ((kr & 7) << 4)));
#pragma unroll
        for (int u = 0; u < 2; ++u) {
          f32x4 acc = {0.f, 0.f, 0.f, 0.f};
#pragma unroll
          for (int s = 0; s < 4; ++s)
            acc = __builtin_amdgcn_mfma_f32_16x16x32_f16(qf[u][s], kf[s], acc, 0, 0, 0);
          int m = ch * 64 + 16 * t + cc;
          int l0 = lb + 32 * w + 16 * u + 4 * g;
#pragma unroll
          for (int rg = 0; rg < 4; ++rg)
            if (m <= l0 + rg) zacc[u][rg] += __expf(acc[rg]);
        }
      }
    }
  }
#pragma unroll
  for (int u = 0; u < 2; ++u)
#pragma unroll
    for (int rg = 0; rg < 4; ++rg) {
      float vv = zacc[u][rg];
      vv += __shfl_xor(vv, 1, 16);
      vv += __shfl_xor(vv, 2, 16);
      vv += __shfl_xor(vv, 4, 16);
      vv += __shfl_xor(vv, 8, 16);
      if (cc == 0)
        Zinv[((long)nb * NHEAD + h) * L_SEQ + lb + 32 * w + 16 * u + 4 * g + rg] =
            1.0f / (8.0f * vv);
    }
}

// ---------------------------------------------------------------------------
// zero_fill: strict-upper 128x128 tiles of w_mean = 0 (d_out is poisoned).
// ---------------------------------------------------------------------------
__global__ __launch_bounds__(256) void zero_fill(float* __restrict__ wmean)
{
  const int by = blockIdx.x, mc = blockIdx.y, nb = blockIdx.z;
  if (mc <= by) return;
  const int tr = threadIdx.x >> 1, th = threadIdx.x & 1;
  float4 z4 = {0.f, 0.f, 0.f, 0.f};
  float* p = wmean + (long)nb * L_SEQ * L_SEQ + (long)(by * 128 + tr) * L_SEQ +
             mc * 128 + th * 64;
#pragma unroll
  for (int j = 0; j < 16; ++j) ((float4*)p)[j] = z4;
}

// ---------------------------------------------------------------------------
// S2: w_mean[n,l,m] = sum_h exp(s_h[l,m]) * Zinv[n,h,l]  on 128x128 triangle
// tiles. Triangle-flattened XCD-swizzled grid (136 blocks/batch). Per head:
// DMA-stage Q+K (64KB), 2 barriers, 64 MFMA/wave + exp accumulation.
// ---------------------------------------------------------------------------
__global__ __launch_bounds__(256) void s2_kernel(
    const _Float16* __restrict__ qp, const _Float16* __restrict__ kp,
    const float* __restrict__ Zinv, float* __restrict__ wmean)
{
  __shared__ __align__(16) _Float16 Qs[128][128];
  __shared__ __align__(16) _Float16 Ks[128][128];
  __shared__ float zl[NHEAD][128];
  const int tid = threadIdx.x, lane = tid & 63, wv = tid >> 6;
  const int g = lane >> 4, cc = lane & 15;
  const int wm = wv >> 1, wn = wv & 1;
  const int nb = blockIdx.y;
  // XCD-aware bijective swizzle (136 = 8*17), then triangle decode (by >= mc)
  int bx = (int)blockIdx.x;
  bx = (bx & 7) * 17 + (bx >> 3);
  int by = 0, rem = bx;
  while (rem > by) { rem -= by + 1; ++by; }
  const int mc = rem;
  const int lb = by * 128, mb = mc * 128;
  const bool diag = (mc == by);
  const int srow = lane >> 4, scl = lane & 15;
  char* QsB = (char*)&Qs[0][0];
  char* KsB = (char*)&Ks[0][0];

  for (int i = tid; i < NHEAD * 128; i += 256)
    zl[i >> 7][i & 127] = Zinv[((long)nb * NHEAD + (i >> 7)) * L_SEQ + lb + (i & 127)];

  f32x4 wacc[4][4] = {};
  for (int h = 0; h < NHEAD; ++h) {
    __syncthreads();                        // prev compute done (h=0: zl visible)
#pragma unroll
    for (int i = 0; i < 8; ++i) {
      int r = 32 * wv + 4 * i + srow;
      int gc = scl ^ (r & 7);
      gl_lds16(&qp[((long)(lb + r) * 4 + nb) * 1024 + h * 128 + gc * 8],
               &Qs[32 * wv + 4 * i][0]);
      gl_lds16(&kp[((long)(mb + r) * 4 + nb) * 1024 + h * 128 + gc * 8],
               &Ks[32 * wv + 4 * i][0]);
    }
    __syncthreads();                        // DMA drained
    f16x8 qf[4][4];
#pragma unroll
    for (int mi = 0; mi < 4; ++mi) {
      int r = wm * 64 + mi * 16 + cc;
#pragma unroll
      for (int s = 0; s < 4; ++s)
        qf[mi][s] = *(const f16x8*)(QsB + r * 256 + ((64 * s + 16 * g) ^ ((r & 7) << 4)));
    }
#pragma unroll
    for (int ni = 0; ni < 4; ++ni) {
      int kr = wn * 64 + ni * 16 + cc;
      f16x8 kf[4];
#pragma unroll
      for (int s = 0; s < 4; ++s)
        kf[s] = *(const f16x8*)(KsB + kr * 256 + ((64 * s + 16 * g) ^ ((kr & 7) << 4)));
      int m = mb + wn * 64 + ni * 16 + cc;
#pragma unroll
      for (int mi = 0; mi < 4; ++mi) {
        f32x4 acc = {0.f, 0.f, 0.f, 0.f};
#pragma unroll
        for (int s = 0; s < 4; ++s)
          acc = __builtin_amdgcn_mfma_f32_16x16x32_f16(qf[mi][s], kf[s], acc, 0, 0, 0);
        int lrow = wm * 64 + mi * 16 + 4 * g;
#pragma unroll
        for (int rg = 0; rg < 4; ++rg) {
          float e = __expf(acc[rg]) * zl[h][lrow + rg];
          if (!diag || m <= lb + lrow + rg) wacc[mi][ni][rg] += e;
        }
      }
    }
  }
  float* wout = wmean + (long)nb * L_SEQ * L_SEQ;
#pragma unroll
  for (int ni = 0; ni < 4; ++ni) {
    int m = mb + wn * 64 + ni * 16 + cc;
#pragma unroll
    for (int mi = 0; mi < 4; ++mi) {
      int l0 = lb + wm * 64 + mi * 16 + 4 * g;
#pragma unroll
      for (int rg = 0; rg < 4; ++rg)
        wout[(long)(l0 + rg) * L_SEQ + m] = wacc[mi][ni][rg];
    }
  }
}

// ---------------------------------------------------------------------------
extern "C" void kernel_launch(void* const* d_in, const int* in_sizes, int n_in,
                              void* d_out, int out_size, void* d_ws, size_t ws_size,
                              hipStream_t stream)
{
  const float* q  = (const float*)d_in[0];
  const float* k  = (const float*)d_in[1];
  const float* v  = (const float*)d_in[2];
  const float* Wq = (const float*)d_in[3];
  const float* bq = (const float*)d_in[4];
  const float* Wk = (const float*)d_in[5];
  const float* bk = (const float*)d_in[6];
  const float* Wv = (const float*)d_in[7];
  const float* bv = (const float*)d_in[8];
  const float* Wo = (const float*)d_in[9];
  const float* bo = (const float*)d_in[10];

  float* out = (float*)d_out;
  float* wmean = out + (long)L_SEQ * NBATCH * DMODEL;

  if (ws_size < (58UL << 20)) return;

  char* ws = (char*)d_ws;
  _Float16* qp   = (_Float16*)(ws);                  // 16 MB (8192x1024)
  _Float16* kp   = (_Float16*)(ws + (16L << 20));    // 16 MB
  _Float16* voT  = (_Float16*)(ws + (32L << 20));    // 16 MB (4x 1024x2048)
  _Float16* WqT  = (_Float16*)(ws + (48L << 20));    // 2 MB
  _Float16* WkT  = (_Float16*)(ws + (50L << 20));    // 2 MB
  _Float16* WoT  = (_Float16*)(ws + (52L << 20));    // 2 MB
  _Float16* WvoT = (_Float16*)(ws + (54L << 20));    // 2 MB
  float*    bvo  = (float*)   (ws + (56L << 20));    // 4 KB
  float*    Zinv = (float*)   (ws + (56L << 20) + (1L << 16));  // 256 KB

  dim3 tb(32, 8, 1);
  transpose_cast_f32<<<dim3(32, 32, 1), tb, 0, stream>>>(Wq, 1024, WqT, 1024);
  transpose_cast_f32<<<dim3(32, 32, 1), tb, 0, stream>>>(Wk, 1024, WkT, 1024);
  transpose_cast_f32<<<dim3(32, 32, 1), tb, 0, stream>>>(Wo, 1024, WoT, 1024);
  bias_proj<<<dim3(4, 1, 1), 256, 0, stream>>>(bv, Wo, bvo);
  // WvoT[j][i] = sum_k WoT[j][k] * Wv[i][k]  = (Wv@Wo)^T
  gemm16<true, false><<<dim3(8, 8, 1), 256, 0, stream>>>(
      WoT, 1024, 0, Wv, 1024, 0,
      (float*)nullptr, 0, 0, WvoT, 1024, 0,
      (const float*)nullptr, 0, 1.0f, 1024, 0);
  // qp = (q @ Wq + bq) * SCALING ; kp = k @ Wk + bk   (f16 out)
  gemm16<false, true><<<dim3(8, 64, 1), 256, 0, stream>>>(
      q, 1024, 0, WqT, 1024, 0,
      (float*)nullptr, 0, 0, qp, 1024, 0,
      bq, 0, SCALING, 1024, 0);
  gemm16<false, true><<<dim3(8, 64, 1), 256, 0, stream>>>(
      k, 1024, 0, WkT, 1024, 0,
      (float*)nullptr, 0, 0, kp, 1024, 0,
      bk, 0, 1.0f, 1024, 0);
  // voT[nb][d][m] = sum_k WvoT[d][k] * v[m,nb,k] + bvo[d]
  gemm16<true, false><<<dim3(16, 8, 4), 256, 0, stream>>>(
      WvoT, 1024, 0, v, 4096, 1024,
      (float*)nullptr, 0, 0, voT, 2048, 2048L * 1024,
      bvo, 1, 1.0f, 1024, 0);
  // Softmax stats, upper-zero fill, head-averaged weights
  s1_kernel<<<dim3(16, NHEAD, NBATCH), 256, 0, stream>>>(qp, kp, Zinv);
  zero_fill<<<dim3(16, 16, NBATCH), 256, 0, stream>>>(wmean);
  s2_kernel<<<dim3(136, NBATCH, 1), 256, 0, stream>>>(qp, kp, Zinv, wmean);
  // out[l,nb,:] = w_mean[nb,l,:] @ voT[nb]^T + bo  (causal K-limit)
  gemm16<false, true><<<dim3(8, 16, 4), 256, 0, stream>>>(
      wmean, 2048, 2048L * 2048, voT, 2048, 2048L * 1024,
      out, 4096, 1024, (_Float16*)nullptr, 0, 0,
      bo, 0, 1.0f, 2048, 1);
}